// Round 19
// baseline (9549.061 us; speedup 1.0000x reference)
//
#include <hip/hip_runtime.h>
#include <stdint.h>

typedef short short8 __attribute__((ext_vector_type(8)));
typedef float f32x4 __attribute__((ext_vector_type(4)));
typedef unsigned short u16;
typedef unsigned long long u64;

#define MFMA16(a, b, c) __builtin_amdgcn_mfma_f32_16x16x32_bf16((a), (b), (c), 0, 0, 0)

#define T_LEN 512
#define BATCH 64
#define EMB_D 512
#define HID 1024
#define VOC 256
#define R0 256                                // h0 ring slots
#define R1 8                                  // h1 ring slots
#define SLOT (BATCH * HID)                    // u16 elems per ring slot (65536)

// -------- workspace layout (bytes) --------
#define OFF_XT    0u                          // int xT[512][64]
#define OFF_EMBT  131072u                     // bf16 embtab[256][512]
#define OFF_WIH0  524288u                     // bf16 [3072][512]
#define OFF_WHH0  3670016u                    // bf16 [3072][1024]
#define OFF_WIH1  9961472u
#define OFF_WHH1  16252928u
#define OFF_WOUT  22544384u                   // bf16 [256][1024]
#define OFF_H0R   23068672u                   // bf16 ring[256][64][1024]  (32 MB)
#define OFF_H1R   56623104u                   // bf16 ring[8][64][1024]    (1 MB)
#define OFF_H1ALL 57671680u                   // bf16 h1_all[512*64][1024] (64 MB)
#define OFF_SYNC  124780544u                  // f0[4][64] + f1[4][64] flag lines (128B)
#define SYNC_BYTES 65536u
#define WS_TOTAL  (OFF_SYNC + SYNC_BYTES)

static __device__ __forceinline__ u16 f2b(float f) {
  uint32_t u = __float_as_uint(f);
  u += 0x7FFFu + ((u >> 16) & 1u);   // round-to-nearest-even
  return (u16)(u >> 16);
}
static __device__ __forceinline__ float sigm(float x) { return 1.0f / (1.0f + __expf(-x)); }

// wave-ballot poll: lane l watches producer l's flag line; exits when ALL >= tgt
static __device__ __forceinline__ void wpoll(unsigned* base, unsigned tgt) {
  unsigned* f = base + (size_t)(threadIdx.x & 63) * 32;
  for (;;) {
    const unsigned v = __hip_atomic_load(f, __ATOMIC_RELAXED, __HIP_MEMORY_SCOPE_AGENT);
    if (__all((int)(v >= tgt))) break;
    __builtin_amdgcn_s_sleep(1);
  }
}

// -------- f32 -> bf16 convert --------
__global__ void cvt_kernel(const float* __restrict__ src, u16* __restrict__ dst, int n) {
  int i = ((int)blockIdx.x * 256 + (int)threadIdx.x) * 4;
  if (i + 4 <= n) {
    const float4 v = *(const float4*)(src + i);
    ushort4 o;
    o.x = f2b(v.x); o.y = f2b(v.y); o.z = f2b(v.z); o.w = f2b(v.w);
    *(ushort4*)(dst + i) = o;
  }
}

// -------- token transpose: xT[t][b] = x[b][t] --------
__global__ void xt_kernel(const int* __restrict__ x, int* __restrict__ xT) {
  const int t = (int)blockIdx.x, b = (int)threadIdx.x;
  xT[t * BATCH + b] = x[b * T_LEN + t];
}

// -------- persistent RNN: 512 wave-autonomous tiles, no LDS, no barriers --------
// blockIdx = bt*128 + layer*64 + ug  ->  %8 == ug%8: weight slice XCD-pinned.
// One wave owns a 16-unit x 16-batch tile with FULL K; C/D layout keeps each
// lane's 4 unit-sums register-local -> gate math + one 8B sc-store, no LDS.
__global__ __launch_bounds__(64, 1) void rnn_persist_kernel(
    const int* __restrict__ xT, const u16* __restrict__ embtab,
    const u16* __restrict__ A0i_r, const u16* __restrict__ A0i_z, const u16* __restrict__ A0i_n,
    const u16* __restrict__ A0h_r, const u16* __restrict__ A0h_z, const u16* __restrict__ A0h_n,
    const u16* __restrict__ A1i_r, const u16* __restrict__ A1i_z, const u16* __restrict__ A1i_n,
    const u16* __restrict__ A1h_r, const u16* __restrict__ A1h_z, const u16* __restrict__ A1h_n,
    const float* __restrict__ bih0, const float* __restrict__ bhh0,
    const float* __restrict__ bih1, const float* __restrict__ bhh1,
    u16* __restrict__ h0r, u16* __restrict__ h1r,
    u16* __restrict__ h1all, unsigned* __restrict__ sync)
{
  const int lane = (int)threadIdx.x;
  const int lrow = lane & 15;
  const int lk8 = (lane >> 4) << 3;
  const int wgid = (int)blockIdx.x;
  const int bt = wgid >> 7;                // batch-block 0..3
  const int layer = (wgid >> 6) & 1;
  const int ug = wgid & 63;                // unit-group (16 units), XCD-pinned

  unsigned* f0 = sync;                     // f0[bt*64+ug] at *32 words (128B lines)
  unsigned* f1 = sync + 4 * 64 * 32;
  unsigned* f0d = f0 + (size_t)(bt * 64) * 32;   // this bt's domain
  unsigned* f1d = f1 + (size_t)(bt * 64) * 32;
  unsigned* myflag = (layer ? f1d : f0d) + (size_t)ug * 32;

  // ---- per-gate weight bases (R6-safe separate args) ----
  const u16 *Axr, *Axz, *Axn, *Ahr, *Ahz, *Ahn;
  int ldx;
  if (layer == 0) { Axr = A0i_r; Axz = A0i_z; Axn = A0i_n;
                    Ahr = A0h_r; Ahz = A0h_z; Ahn = A0h_n; ldx = EMB_D; }
  else            { Axr = A1i_r; Axz = A1i_z; Axn = A1i_n;
                    Ahr = A1h_r; Ahz = A1h_z; Ahn = A1h_n; ldx = HID; }
  const int urow = ug * 16 + lrow;
  const size_t axrow = (size_t)urow * ldx;
  const size_t ahrow = (size_t)urow * HID;
  const int brow = bt * 16 + lrow;         // activation row (batch)

  // ---- per-lane epilogue constants: 4 consecutive units x 1 batch ----
  const float* bi = layer ? bih1 : bih0;
  const float* bh = layer ? bhh1 : bhh0;
  const int ub4 = (lane >> 4) * 4;                 // unit-in-tile base
  const int eu0 = ug * 16 + ub4;                   // global unit base
  const int eb = bt * 16 + lrow;                   // global batch
  float bR[4], bZ[4], bNi[4], bNh[4], hp[4];
#pragma unroll
  for (int r = 0; r < 4; ++r) {
    const int ugl = eu0 + r;
    bR[r] = bi[ugl] + bh[ugl];
    bZ[r] = bi[HID + ugl] + bh[HID + ugl];
    bNi[r] = bi[2 * HID + ugl];
    bNh[r] = bh[2 * HID + ugl];
    hp[r] = 0.f;
  }
  const size_t hoff = (size_t)eb * HID + eu0;      // 8B-aligned

  const int sBeg = layer ? 1 : 0;
  const int sEnd = layer ? T_LEN : (T_LEN - 1);

  for (int s = sBeg; s <= sEnd; ++s) {
    // ---- dependency polls (wave-ballot, per-bt domain) ----
    wpoll(f0d, (unsigned)s);                       // h0(s-1) ready
    if (layer) wpoll(f1d, (unsigned)(s - 1));      // h1(s-2) ready (2-step slack)
    else if (s >= 252) wpoll(f1d, (unsigned)(s - 250));  // h0-ring back-pressure

    const u16* h0prev = h0r + (size_t)((s - 1) & (R0 - 1)) * SLOT;
    const u16* h1prev = h1r + (size_t)((s - 2) & (R1 - 1)) * SLOT;

    f32x4 aR = {0.f, 0.f, 0.f, 0.f}, aZ = aR, aNi = aR, aNh = aR;

    if (layer == 0) {
      // emb part -> r,z,ni  (K = 512)
      const int tok = xT[s * BATCH + brow];
      const u16* Bx = embtab + (size_t)tok * EMB_D;
#pragma unroll 4
      for (int ks = 0; ks < 16; ++ks) {
        const int kk = ks * 32 + lk8;
        const short8 ar = *(const short8*)(Axr + axrow + kk);
        const short8 az = *(const short8*)(Axz + axrow + kk);
        const short8 an = *(const short8*)(Axn + axrow + kk);
        const short8 bf = *(const short8*)(Bx + kk);
        aR = MFMA16(ar, bf, aR);
        aZ = MFMA16(az, bf, aZ);
        aNi = MFMA16(an, bf, aNi);
      }
      // h part -> r,z,nh  (K = 1024)
      const u16* Bh = h0prev + (size_t)brow * HID;
#pragma unroll 4
      for (int ks = 0; ks < 32; ++ks) {
        const int kk = ks * 32 + lk8;
        const short8 ar = *(const short8*)(Ahr + ahrow + kk);
        const short8 az = *(const short8*)(Ahz + ahrow + kk);
        const short8 an = *(const short8*)(Ahn + ahrow + kk);
        const short8 bf = *(const short8*)(Bh + kk);
        aR = MFMA16(ar, bf, aR);
        aZ = MFMA16(az, bf, aZ);
        aNh = MFMA16(an, bf, aNh);
      }
    } else {
      // ih part (h0(s-1)) -> r,z,ni
      const u16* Bx = h0prev + (size_t)brow * HID;
#pragma unroll 4
      for (int ks = 0; ks < 32; ++ks) {
        const int kk = ks * 32 + lk8;
        const short8 ar = *(const short8*)(Axr + axrow + kk);
        const short8 az = *(const short8*)(Axz + axrow + kk);
        const short8 an = *(const short8*)(Axn + axrow + kk);
        const short8 bf = *(const short8*)(Bx + kk);
        aR = MFMA16(ar, bf, aR);
        aZ = MFMA16(az, bf, aZ);
        aNi = MFMA16(an, bf, aNi);
      }
      // hh part (h1(s-2)) -> r,z,nh
      const u16* Bh = h1prev + (size_t)brow * HID;
#pragma unroll 4
      for (int ks = 0; ks < 32; ++ks) {
        const int kk = ks * 32 + lk8;
        const short8 ar = *(const short8*)(Ahr + ahrow + kk);
        const short8 az = *(const short8*)(Ahz + ahrow + kk);
        const short8 an = *(const short8*)(Ahn + ahrow + kk);
        const short8 bf = *(const short8*)(Bh + kk);
        aR = MFMA16(ar, bf, aR);
        aZ = MFMA16(az, bf, aZ);
        aNh = MFMA16(an, bf, aNh);
      }
    }

    // ---- epilogue: all in-register (C/D: unit = ub4+r, batch = lrow) ----
    u16 hv[4];
#pragma unroll
    for (int r = 0; r < 4; ++r) {
      const float rg = sigm(aR[r] + bR[r]);
      const float zg = sigm(aZ[r] + bZ[r]);
      const float ng = tanhf(aNi[r] + bNi[r] + rg * (aNh[r] + bNh[r]));
      const float hn = (1.0f - zg) * ng + zg * hp[r];
      hp[r] = hn;
      hv[r] = f2b(hn);
    }
    const u64 packed = (u64)hv[0] | ((u64)hv[1] << 16) | ((u64)hv[2] << 32) | ((u64)hv[3] << 48);
    u16* wslot = layer ? (h1r + (size_t)((s - 1) & (R1 - 1)) * SLOT)
                       : (h0r + (size_t)(s & (R0 - 1)) * SLOT);
    __hip_atomic_store((u64*)(wslot + hoff), packed,
                       __ATOMIC_RELAXED, __HIP_MEMORY_SCOPE_AGENT);

    // ---- publish: drain ring store, then per-wave flag ----
    asm volatile("s_waitcnt vmcnt(0)" ::: "memory");
    if (lane == 0)
      __hip_atomic_store(myflag, (unsigned)(layer ? s : s + 1),
                         __ATOMIC_RELAXED, __HIP_MEMORY_SCOPE_AGENT);
    // h1all streaming store AFTER publish (off critical path; non-allocating)
    if (layer)
      __hip_atomic_store((u64*)(h1all + ((size_t)(s - 1) * BATCH + eb) * HID + eu0),
                         packed, __ATOMIC_RELAXED, __HIP_MEMORY_SCOPE_AGENT);
  }
}

// -------- epilogue logits (R5-verified MFMA path, decode-0) --------
__global__ __launch_bounds__(256, 2) void logits_kernel(
    const u16* __restrict__ h1all, const u16* __restrict__ Woutb,
    const float* __restrict__ bout, float* __restrict__ out)
{
  __shared__ __align__(16) short lds[16 * 4 * 64 * 8];
  const int tid = (int)threadIdx.x;
  const int wv = tid >> 6, lane = tid & 63;
  const int lrow = lane & 15, lk8 = (lane >> 4) << 3;
  const int row0 = (int)blockIdx.x * 64 + wv * 16;
  f32x4 acc[16];
#pragma unroll
  for (int i = 0; i < 16; ++i) acc[i] = (f32x4){0.f, 0.f, 0.f, 0.f};

  for (int kc = 0; kc < HID; kc += 128) {
    __syncthreads();
#pragma unroll
    for (int j = 0; j < 16; ++j) {
      const int slot = tid + j * 256;
      const int ct = slot >> 8, kt = (slot >> 6) & 3, l = slot & 63;
      *(short8*)&lds[slot * 8] =
          *(const short8*)(Woutb + (size_t)(ct * 16 + (l & 15)) * HID + kc + kt * 32 + ((l >> 4) << 3));
    }
    __syncthreads();
#pragma unroll
    for (int kt = 0; kt < 4; ++kt) {
      const short8 af = *(const short8*)(h1all + (size_t)(row0 + lrow) * HID + kc + kt * 32 + lk8);
#pragma unroll
      for (int ct = 0; ct < 16; ++ct) {
        const short8 bf = *(const short8*)&lds[((ct * 4 + kt) * 64 + lane) * 8];
        acc[ct] = MFMA16(af, bf, acc[ct]);
      }
    }
  }
#pragma unroll
  for (int ct = 0; ct < 16; ++ct) {
    const int v = ct * 16 + lrow;
    const float bo = bout[v];
#pragma unroll
    for (int r = 0; r < 4; ++r) {
      const int row = row0 + (lane >> 4) * 4 + r;  // row = t*64 + b
      const int t = row >> 6, b = row & 63;
      out[((size_t)(b * T_LEN + t)) * VOC + v] = acc[ct][r] + bo;
    }
  }
}

extern "C" void kernel_launch(void* const* d_in, const int* in_sizes, int n_in,
                              void* d_out, int out_size, void* d_ws, size_t ws_size,
                              hipStream_t stream) {
  const int*   x     = (const int*)d_in[0];
  const float* embed = (const float*)d_in[1];
  const float* Wih0  = (const float*)d_in[2];
  const float* Whh0  = (const float*)d_in[3];
  const float* bih0  = (const float*)d_in[4];
  const float* bhh0  = (const float*)d_in[5];
  const float* Wih1  = (const float*)d_in[6];
  const float* Whh1  = (const float*)d_in[7];
  const float* bih1  = (const float*)d_in[8];
  const float* bhh1  = (const float*)d_in[9];
  const float* Wout  = (const float*)d_in[10];
  const float* bout  = (const float*)d_in[11];
  float* out = (float*)d_out;
  char* ws = (char*)d_ws;
  if (ws_size < (size_t)WS_TOTAL) return;

  // zero: h0 ring slot 255 (h0(-1)=0), h1 ring slot 7 (h1(-1)=0), flags
  hipMemsetAsync(ws + OFF_H0R + (size_t)(R0 - 1) * SLOT * 2, 0, SLOT * 2, stream);
  hipMemsetAsync(ws + OFF_H1R + (size_t)(R1 - 1) * SLOT * 2, 0, SLOT * 2, stream);
  hipMemsetAsync(ws + OFF_SYNC, 0, SYNC_BYTES, stream);
  xt_kernel<<<512, 64, 0, stream>>>(x, (int*)(ws + OFF_XT));
  cvt_kernel<<<128, 256, 0, stream>>>(embed, (u16*)(ws + OFF_EMBT), 256 * 512);
  cvt_kernel<<<1536, 256, 0, stream>>>(Wih0, (u16*)(ws + OFF_WIH0), 3072 * 512);
  cvt_kernel<<<3072, 256, 0, stream>>>(Whh0, (u16*)(ws + OFF_WHH0), 3072 * 1024);
  cvt_kernel<<<3072, 256, 0, stream>>>(Wih1, (u16*)(ws + OFF_WIH1), 3072 * 1024);
  cvt_kernel<<<3072, 256, 0, stream>>>(Whh1, (u16*)(ws + OFF_WHH1), 3072 * 1024);
  cvt_kernel<<<256, 256, 0, stream>>>(Wout, (u16*)(ws + OFF_WOUT), 256 * 1024);

  const u16* wih0b = (const u16*)(ws + OFF_WIH0);
  const u16* whh0b = (const u16*)(ws + OFF_WHH0);
  const u16* wih1b = (const u16*)(ws + OFF_WIH1);
  const u16* whh1b = (const u16*)(ws + OFF_WHH1);

  rnn_persist_kernel<<<512, 64, 0, stream>>>(
      (const int*)(ws + OFF_XT), (const u16*)(ws + OFF_EMBT),
      wih0b, wih0b + 524288, wih0b + 1048576,
      whh0b, whh0b + 1048576, whh0b + 2097152,
      wih1b, wih1b + 1048576, wih1b + 2097152,
      whh1b, whh1b + 1048576, whh1b + 2097152,
      bih0, bhh0, bih1, bhh1,
      (u16*)(ws + OFF_H0R), (u16*)(ws + OFF_H1R),
      (u16*)(ws + OFF_H1ALL), (unsigned*)(ws + OFF_SYNC));

  logits_kernel<<<512, 256, 0, stream>>>((const u16*)(ws + OFF_H1ALL),
                                         (const u16*)(ws + OFF_WOUT), bout, out);
}

// Round 20
// 7785.464 us; speedup vs baseline: 1.2265x; 1.2265x over previous
//
#include <hip/hip_runtime.h>
#include <stdint.h>

typedef short short8 __attribute__((ext_vector_type(8)));
typedef float f32x4 __attribute__((ext_vector_type(4)));
typedef unsigned short u16;

#define MFMA16(a, b, c) __builtin_amdgcn_mfma_f32_16x16x32_bf16((a), (b), (c), 0, 0, 0)

#define T_LEN 512
#define BATCH 64
#define EMB_D 512
#define HID 1024
#define VOC 256
#define NWG 128
#define RNN_THREADS 512
#define R0 256                                // h0 ring slots
#define R1 8                                  // h1 ring slots
#define SLOT (BATCH * HID)                    // u16 elems per ring slot (65536)

// -------- workspace layout (bytes) --------
#define OFF_XT    0u                          // int xT[512][64]
#define OFF_EMBT  131072u                     // bf16 embtab[256][512]
#define OFF_WIH0  524288u                     // bf16 [3072][512]
#define OFF_WHH0  3670016u                    // bf16 [3072][1024]
#define OFF_WIH1  9961472u
#define OFF_WHH1  16252928u
#define OFF_WOUT  22544384u                   // bf16 [256][1024]
#define OFF_H0R   23068672u                   // bf16 ring[256][64][1024]  (32 MB)
#define OFF_H1R   56623104u                   // bf16 ring[8][64][1024]    (1 MB)
#define OFF_H1ALL 57671680u                   // bf16 h1_all[512*64][1024] (64 MB)
#define OFF_SYNC  124780544u                  // p0[64]+p1[64] flag lines, 128B apart
#define SYNC_BYTES 16640u
#define WS_TOTAL  (OFF_SYNC + SYNC_BYTES)

static __device__ __forceinline__ u16 f2b(float f) {
  uint32_t u = __float_as_uint(f);
  u += 0x7FFFu + ((u >> 16) & 1u);   // round-to-nearest-even
  return (u16)(u >> 16);
}
static __device__ __forceinline__ float sigm(float x) { return 1.0f / (1.0f + __expf(-x)); }

// -------- f32 -> bf16 convert --------
__global__ void cvt_kernel(const float* __restrict__ src, u16* __restrict__ dst, int n) {
  int i = ((int)blockIdx.x * 256 + (int)threadIdx.x) * 4;
  if (i + 4 <= n) {
    const float4 v = *(const float4*)(src + i);
    ushort4 o;
    o.x = f2b(v.x); o.y = f2b(v.y); o.z = f2b(v.z); o.w = f2b(v.w);
    *(ushort4*)(dst + i) = o;
  }
}

// -------- token transpose: xT[t][b] = x[b][t] --------
__global__ void xt_kernel(const int* __restrict__ x, int* __restrict__ xT) {
  const int t = (int)blockIdx.x, b = (int)threadIdx.x;
  xT[t * BATCH + b] = x[b * T_LEN + t];
}

// poll with BUSY spin (no s_sleep): keeps waves issuing VALU so the clock
// governor sees an active workload (R20 single-variable change vs R13).
static __device__ __forceinline__ void poll_flags(unsigned* p0, unsigned* p1,
                                                  unsigned t0, unsigned t1, int tid) {
  if (tid < 128) {
    unsigned* f = (tid < 64) ? (p0 + (size_t)tid * 32) : (p1 + (size_t)(tid - 64) * 32);
    const unsigned tgt = (tid < 64) ? t0 : t1;
    float junk = (float)tid;
    for (;;) {
      const unsigned v = __hip_atomic_load(f, __ATOMIC_RELAXED, __HIP_MEMORY_SCOPE_AGENT);
      if (v >= tgt) break;
      // live VALU chain (kept by sink) -- no sleep, stay clock-resident
#pragma unroll
      for (int i = 0; i < 8; ++i) junk = __builtin_fmaf(junk, 1.000001f, 0.5f);
      asm volatile("" :: "v"(junk));
    }
  }
  __syncthreads();
}

// -------- persistent RNN, decoupled chains (R13 verbatim except poll spin) --------
__global__ __launch_bounds__(RNN_THREADS, 1) void rnn_persist_kernel(
    const int* __restrict__ xT, const u16* __restrict__ embtab,
    const u16* __restrict__ A0i_r, const u16* __restrict__ A0i_z, const u16* __restrict__ A0i_n,
    const u16* __restrict__ A0h_r, const u16* __restrict__ A0h_z, const u16* __restrict__ A0h_n,
    const u16* __restrict__ A1i_r, const u16* __restrict__ A1i_z, const u16* __restrict__ A1i_n,
    const u16* __restrict__ A1h_r, const u16* __restrict__ A1h_z, const u16* __restrict__ A1h_n,
    const float* __restrict__ bih0, const float* __restrict__ bhh0,
    const float* __restrict__ bih1, const float* __restrict__ bhh1,
    u16* __restrict__ h0r, u16* __restrict__ h1r,
    u16* __restrict__ h1all, unsigned* __restrict__ sync)
{
  __shared__ __align__(16) float lds[16384];
  const int tid = (int)threadIdx.x;
  const int wv = tid >> 6;
  const int lane = tid & 63;
  const int lrow = lane & 15;
  const int lk8 = (lane >> 4) << 3;
  const int wgid = (int)blockIdx.x;
  const int layer = wgid >> 6;
  const int ubase = (wgid & 63) << 4;
  const bool iwave = (wv < 4);
  const bool l0i = (layer == 0) && iwave;
  unsigned* p0 = sync;
  unsigned* p1 = sync + 64 * 32;

  // ---- role-uniform A config (R7-validated per-gate pointers) ----
  const u16 *Ar, *Az, *An;
  int ldb, k0;
  if (layer == 0) {
    if (iwave) { Ar = A0i_r; Az = A0i_z; An = A0i_n; ldb = EMB_D; k0 = wv * 128; }
    else       { Ar = A0h_r; Az = A0h_z; An = A0h_n; ldb = HID;   k0 = (wv - 4) * 256; }
  } else {
    if (iwave) { Ar = A1i_r; Az = A1i_z; An = A1i_n; ldb = HID;   k0 = wv * 256; }
    else       { Ar = A1h_r; Az = A1h_z; An = A1h_n; ldb = HID;   k0 = (wv - 4) * 256; }
  }
  const size_t arow = (size_t)(ubase + lrow) * ldb;

  // ---- epilogue constants: thread owns unit-pair (u0,u0+1) x batch eb ----
  const float* bi = layer ? bih1 : bih0;
  const float* bh = layer ? bhh1 : bhh0;
  const int u0 = (tid & 7) * 2;
  const int eb = tid >> 3;
  const int eug0 = ubase + u0, eug1 = eug0 + 1;
  const float bR0 = bi[eug0] + bh[eug0];
  const float bZ0 = bi[HID + eug0] + bh[HID + eug0];
  const float bNi0 = bi[2 * HID + eug0];
  const float bNh0 = bh[2 * HID + eug0];
  const float bR1 = bi[eug1] + bh[eug1];
  const float bZ1 = bi[HID + eug1] + bh[HID + eug1];
  const float bNi1 = bi[2 * HID + eug1];
  const float bNh1 = bh[2 * HID + eug1];
  const int l_e = ((u0 >> 2) << 4) | (eb & 15);
  const int r0 = u0 & 3, r1 = r0 + 1;
  const int ebt = eb >> 4;
  const int ix0 = l_e ^ (r0 << 3), ix1 = l_e ^ (r1 << 3);
  float hp0 = 0.f, hp1 = 0.f;

  const int sBeg = (layer == 0) ? 0 : 1;
  const int sEnd = (layer == 0) ? (T_LEN - 1) : T_LEN;

  for (int s = sBeg; s <= sEnd; ++s) {
    // ---- dependency poll ----
    if (layer == 0) {
      const unsigned bp = (s >= 252) ? (unsigned)(s - 250) : 0u;  // h0-ring back-pressure
      poll_flags(p0, p1, (unsigned)s, bp, tid);
    } else {
      poll_flags(p0, p1, (unsigned)s, (unsigned)(s - 1), tid);
    }

    {
      const u16* h0prev = h0r + (size_t)((s - 1) & (R0 - 1)) * SLOT;
      const u16* h1prev = h1r + (size_t)((s - 2) & (R1 - 1)) * SLOT;

      f32x4 acc0[4], acc1[4], accn[4];
#pragma unroll
      for (int bt = 0; bt < 4; ++bt) {
        acc0[bt] = (f32x4){0.f, 0.f, 0.f, 0.f};
        acc1[bt] = (f32x4){0.f, 0.f, 0.f, 0.f};
        accn[bt] = (f32x4){0.f, 0.f, 0.f, 0.f};
      }
      if (l0i) {  // B = embed rows gathered by token (embtab L2-resident)
        const u16* brow[4];
#pragma unroll
        for (int bt = 0; bt < 4; ++bt) {
          const int tok = xT[s * BATCH + bt * 16 + lrow];
          brow[bt] = embtab + (size_t)tok * EMB_D;
        }
#pragma unroll
        for (int ks = 0; ks < 4; ++ks) {
          const int kk = k0 + ks * 32 + lk8;
          const short8 ar = *(const short8*)(Ar + arow + kk);
          const short8 az = *(const short8*)(Az + arow + kk);
          const short8 an = *(const short8*)(An + arow + kk);
          const short8 b0 = *(const short8*)(brow[0] + kk);
          const short8 b1 = *(const short8*)(brow[1] + kk);
          const short8 b2 = *(const short8*)(brow[2] + kk);
          const short8 b3 = *(const short8*)(brow[3] + kk);
          acc0[0] = MFMA16(ar, b0, acc0[0]); acc1[0] = MFMA16(az, b0, acc1[0]); accn[0] = MFMA16(an, b0, accn[0]);
          acc0[1] = MFMA16(ar, b1, acc0[1]); acc1[1] = MFMA16(az, b1, acc1[1]); accn[1] = MFMA16(an, b1, accn[1]);
          acc0[2] = MFMA16(ar, b2, acc0[2]); acc1[2] = MFMA16(az, b2, acc1[2]); accn[2] = MFMA16(an, b2, accn[2]);
          acc0[3] = MFMA16(ar, b3, acc0[3]); acc1[3] = MFMA16(az, b3, acc1[3]); accn[3] = MFMA16(an, b3, accn[3]);
        }
      } else {    // B = h ring slot (cached cold-miss reads, L2-amortized per XCD)
        const u16* Bp;
        if (layer == 0) Bp = h0prev;
        else            Bp = iwave ? h0prev : h1prev;
#pragma unroll
        for (int ks = 0; ks < 8; ++ks) {
          const int kk = k0 + ks * 32 + lk8;
          const short8 ar = *(const short8*)(Ar + arow + kk);
          const short8 az = *(const short8*)(Az + arow + kk);
          const short8 an = *(const short8*)(An + arow + kk);
#pragma unroll
          for (int bt = 0; bt < 4; ++bt) {
            const short8 bf = *(const short8*)(Bp + (size_t)(bt * 16 + lrow) * HID + kk);
            acc0[bt] = MFMA16(ar, bf, acc0[bt]);
            acc1[bt] = MFMA16(az, bf, acc1[bt]);
            accn[bt] = MFMA16(an, bf, accn[bt]);
          }
        }
      }
      // reduction round 1: i-waves store groups {0,1,2} (XOR-swizzled)
      if (iwave) {
#pragma unroll
        for (int bt = 0; bt < 4; ++bt)
#pragma unroll
          for (int r = 0; r < 4; ++r) {
            const int ix = lane ^ (r << 3);
            lds[(((wv * 4 + 0) * 4 + bt) * 256) + r * 64 + ix] = acc0[bt][r];
            lds[(((wv * 4 + 1) * 4 + bt) * 256) + r * 64 + ix] = acc1[bt][r];
            lds[(((wv * 4 + 2) * 4 + bt) * 256) + r * 64 + ix] = accn[bt][r];
          }
      }
      __syncthreads();
      // reduction round 2: h-waves add groups {0,1}, store group 3
      if (!iwave) {
        const int z = wv - 4;
#pragma unroll
        for (int bt = 0; bt < 4; ++bt)
#pragma unroll
          for (int r = 0; r < 4; ++r) {
            const int ix = lane ^ (r << 3);
            float* q0 = &lds[(((z * 4 + 0) * 4 + bt) * 256) + r * 64 + ix];
            float* q1 = &lds[(((z * 4 + 1) * 4 + bt) * 256) + r * 64 + ix];
            *q0 = *q0 + acc0[bt][r];
            *q1 = *q1 + acc1[bt][r];
            lds[(((z * 4 + 3) * 4 + bt) * 256) + r * 64 + ix] = accn[bt][r];
          }
      }
      __syncthreads();
      // epilogue: gate math (validated), packed 4B relaxed-atomic h-store to ring
      {
        float sr0 = 0.f, sz0 = 0.f, sni0 = 0.f, snh0 = 0.f;
        float sr1 = 0.f, sz1 = 0.f, sni1 = 0.f, snh1 = 0.f;
#pragma unroll
        for (int z = 0; z < 4; ++z) {
          sr0  += lds[(((z * 4 + 0) * 4 + ebt) * 256) + r0 * 64 + ix0];
          sz0  += lds[(((z * 4 + 1) * 4 + ebt) * 256) + r0 * 64 + ix0];
          sni0 += lds[(((z * 4 + 2) * 4 + ebt) * 256) + r0 * 64 + ix0];
          snh0 += lds[(((z * 4 + 3) * 4 + ebt) * 256) + r0 * 64 + ix0];
          sr1  += lds[(((z * 4 + 0) * 4 + ebt) * 256) + r1 * 64 + ix1];
          sz1  += lds[(((z * 4 + 1) * 4 + ebt) * 256) + r1 * 64 + ix1];
          sni1 += lds[(((z * 4 + 2) * 4 + ebt) * 256) + r1 * 64 + ix1];
          snh1 += lds[(((z * 4 + 3) * 4 + ebt) * 256) + r1 * 64 + ix1];
        }
        const float rg0 = sigm(sr0 + bR0);
        const float zg0 = sigm(sz0 + bZ0);
        const float ng0 = tanhf(sni0 + bNi0 + rg0 * (snh0 + bNh0));
        const float hn0 = (1.0f - zg0) * ng0 + zg0 * hp0;
        const float rg1 = sigm(sr1 + bR1);
        const float zg1 = sigm(sz1 + bZ1);
        const float ng1 = tanhf(sni1 + bNi1 + rg1 * (snh1 + bNh1));
        const float hn1 = (1.0f - zg1) * ng1 + zg1 * hp1;
        hp0 = hn0; hp1 = hn1;
        const unsigned packed = (unsigned)f2b(hn0) | ((unsigned)f2b(hn1) << 16);
        u16* wslot = layer ? (h1r + (size_t)((s - 1) & (R1 - 1)) * SLOT)
                           : (h0r + (size_t)(s & (R0 - 1)) * SLOT);
        __hip_atomic_store((unsigned*)&wslot[eb * HID + eug0], packed,
                           __ATOMIC_RELAXED, __HIP_MEMORY_SCOPE_AGENT);
        if (layer)
          *(unsigned*)&h1all[((size_t)(s - 1) * BATCH + eb) * HID + eug0] = packed;
      }
    }
    // ---- publish progress: syncthreads drains vmcnt, then relaxed flag store ----
    __syncthreads();
    if (tid == 0) {
      unsigned* f = layer ? (p1 + (size_t)(wgid - 64) * 32) : (p0 + (size_t)wgid * 32);
      __hip_atomic_store(f, (unsigned)(s + (layer ? 0 : 1)), __ATOMIC_RELAXED,
                         __HIP_MEMORY_SCOPE_AGENT);
    }
  }
}

// -------- epilogue logits (R5-verified MFMA path, decode-0) --------
__global__ __launch_bounds__(256, 2) void logits_kernel(
    const u16* __restrict__ h1all, const u16* __restrict__ Woutb,
    const float* __restrict__ bout, float* __restrict__ out)
{
  __shared__ __align__(16) short lds[16 * 4 * 64 * 8];
  const int tid = (int)threadIdx.x;
  const int wv = tid >> 6, lane = tid & 63;
  const int lrow = lane & 15, lk8 = (lane >> 4) << 3;
  const int row0 = (int)blockIdx.x * 64 + wv * 16;
  f32x4 acc[16];
#pragma unroll
  for (int i = 0; i < 16; ++i) acc[i] = (f32x4){0.f, 0.f, 0.f, 0.f};

  for (int kc = 0; kc < HID; kc += 128) {
    __syncthreads();
#pragma unroll
    for (int j = 0; j < 16; ++j) {
      const int slot = tid + j * 256;
      const int ct = slot >> 8, kt = (slot >> 6) & 3, l = slot & 63;
      *(short8*)&lds[slot * 8] =
          *(const short8*)(Woutb + (size_t)(ct * 16 + (l & 15)) * HID + kc + kt * 32 + ((l >> 4) << 3));
    }
    __syncthreads();
#pragma unroll
    for (int kt = 0; kt < 4; ++kt) {
      const short8 af = *(const short8*)(h1all + (size_t)(row0 + lrow) * HID + kc + kt * 32 + lk8);
#pragma unroll
      for (int ct = 0; ct < 16; ++ct) {
        const short8 bf = *(const short8*)&lds[((ct * 4 + kt) * 64 + lane) * 8];
        acc[ct] = MFMA16(af, bf, acc[ct]);
      }
    }
  }
#pragma unroll
  for (int ct = 0; ct < 16; ++ct) {
    const int v = ct * 16 + lrow;
    const float bo = bout[v];
#pragma unroll
    for (int r = 0; r < 4; ++r) {
      const int row = row0 + (lane >> 4) * 4 + r;  // row = t*64 + b
      const int t = row >> 6, b = row & 63;
      out[((size_t)(b * T_LEN + t)) * VOC + v] = acc[ct][r] + bo;
    }
  }
}

extern "C" void kernel_launch(void* const* d_in, const int* in_sizes, int n_in,
                              void* d_out, int out_size, void* d_ws, size_t ws_size,
                              hipStream_t stream) {
  const int*   x     = (const int*)d_in[0];
  const float* embed = (const float*)d_in[1];
  const float* Wih0  = (const float*)d_in[2];
  const float* Whh0  = (const float*)d_in[3];
  const float* bih0  = (const float*)d_in[4];
  const float* bhh0  = (const float*)d_in[5];
  const float* Wih1  = (const float*)d_in[6];
  const float* Whh1  = (const float*)d_in[7];
  const float* bih1  = (const float*)d_in[8];
  const float* bhh1  = (const float*)d_in[9];
  const float* Wout  = (const float*)d_in[10];
  const float* bout  = (const float*)d_in[11];
  float* out = (float*)d_out;
  char* ws = (char*)d_ws;
  if (ws_size < (size_t)WS_TOTAL) return;

  // zero: h0 ring slot 255 (h0(-1)=0), h1 ring slot 7 (h1(-1)=0), flags
  hipMemsetAsync(ws + OFF_H0R + (size_t)(R0 - 1) * SLOT * 2, 0, SLOT * 2, stream);
  hipMemsetAsync(ws + OFF_H1R + (size_t)(R1 - 1) * SLOT * 2, 0, SLOT * 2, stream);
  hipMemsetAsync(ws + OFF_SYNC, 0, SYNC_BYTES, stream);
  xt_kernel<<<512, 64, 0, stream>>>(x, (int*)(ws + OFF_XT));
  cvt_kernel<<<128, 256, 0, stream>>>(embed, (u16*)(ws + OFF_EMBT), 256 * 512);
  cvt_kernel<<<1536, 256, 0, stream>>>(Wih0, (u16*)(ws + OFF_WIH0), 3072 * 512);
  cvt_kernel<<<3072, 256, 0, stream>>>(Whh0, (u16*)(ws + OFF_WHH0), 3072 * 1024);
  cvt_kernel<<<3072, 256, 0, stream>>>(Wih1, (u16*)(ws + OFF_WIH1), 3072 * 1024);
  cvt_kernel<<<3072, 256, 0, stream>>>(Whh1, (u16*)(ws + OFF_WHH1), 3072 * 1024);
  cvt_kernel<<<256, 256, 0, stream>>>(Wout, (u16*)(ws + OFF_WOUT), 256 * 1024);

  const u16* wih0b = (const u16*)(ws + OFF_WIH0);
  const u16* whh0b = (const u16*)(ws + OFF_WHH0);
  const u16* wih1b = (const u16*)(ws + OFF_WIH1);
  const u16* whh1b = (const u16*)(ws + OFF_WHH1);

  rnn_persist_kernel<<<NWG, RNN_THREADS, 0, stream>>>(
      (const int*)(ws + OFF_XT), (const u16*)(ws + OFF_EMBT),
      wih0b, wih0b + 524288, wih0b + 1048576,
      whh0b, whh0b + 1048576, whh0b + 2097152,
      wih1b, wih1b + 1048576, wih1b + 2097152,
      whh1b, whh1b + 1048576, whh1b + 2097152,
      bih0, bhh0, bih1, bhh1,
      (u16*)(ws + OFF_H0R), (u16*)(ws + OFF_H1R),
      (u16*)(ws + OFF_H1ALL), (unsigned*)(ws + OFF_SYNC));

  logits_kernel<<<512, 256, 0, stream>>>((const u16*)(ws + OFF_H1ALL),
                                         (const u16*)(ws + OFF_WOUT), bout, out);
}